// Round 12
// baseline (170.463 us; speedup 1.0000x reference)
//
#include <hip/hip_runtime.h>

typedef __attribute__((ext_vector_type(8))) short short8;
typedef __attribute__((ext_vector_type(4))) float f32x4;
typedef __attribute__((ext_vector_type(16))) float f32x16;
typedef __attribute__((ext_vector_type(4))) int i32x4;

__device__ __forceinline__ unsigned short f2bf(float f){
  union { float f; unsigned int u; } cv; cv.f = f;
  unsigned int u = cv.u;
  u = (u + 0x7fffu + ((u >> 16) & 1u)) >> 16;
  return (unsigned short)u;
}
__device__ __forceinline__ float bf2f(unsigned short h){
  union { unsigned int u; float f; } cv; cv.u = ((unsigned int)h) << 16;
  return cv.f;
}

typedef unsigned int u32g __attribute__((address_space(1)));
typedef unsigned int u32l __attribute__((address_space(3)));
__device__ __forceinline__ void gload16(const void* g, void* l){
  __builtin_amdgcn_global_load_lds((const u32g*)g, (u32l*)l, 16, 0, 0);
}

__device__ __forceinline__ unsigned int cvtpk_bf16(float lo, float hi){
  unsigned int r;
  asm("v_cvt_pk_bf16_f32 %0, %1, %2" : "=v"(r) : "v"(lo), "v"(hi));
  return r;
}
__device__ __forceinline__ unsigned int cvt2_fp8(float a, float b){
  unsigned int r;
  asm("v_cvt_pk_fp8_f32 %0, %1, %2" : "=v"(r) : "v"(a), "v"(b));
  return r;
}

#define BARRIER() asm volatile("s_barrier" ::: "memory")
#define WAITV(N)  asm volatile("s_waitcnt vmcnt(" #N ")" ::: "memory")
#define WAITLGKM0() asm volatile("s_waitcnt lgkmcnt(0)" ::: "memory")

// ---------------- reduction: per-batch mean / rstd ----------------
__global__ __launch_bounds__(256) void reduce_partial_k(const float* __restrict__ x,
                                                        float2* __restrict__ partial){
  const int b = blockIdx.y, blk = blockIdx.x;
  const float4* xp = (const float4*)(x + (size_t)b*1048576 + (size_t)blk*16384);
  float s = 0.f, sq = 0.f;
  #pragma unroll
  for (int i = 0; i < 16; ++i){
    float4 v = xp[threadIdx.x + i*256];
    s  += v.x + v.y + v.z + v.w;
    sq += v.x*v.x + v.y*v.y + v.z*v.z + v.w*v.w;
  }
  #pragma unroll
  for (int m = 1; m < 64; m <<= 1){ s += __shfl_xor(s, m); sq += __shfl_xor(sq, m); }
  __shared__ float2 acc[4];
  if ((threadIdx.x & 63) == 0) acc[threadIdx.x >> 6] = make_float2(s, sq);
  __syncthreads();
  if (threadIdx.x == 0){
    float S = 0.f, Q = 0.f;
    for (int i = 0; i < 4; ++i){ S += acc[i].x; Q += acc[i].y; }
    partial[b*64 + blk] = make_float2(S, Q);
  }
}

__global__ __launch_bounds__(256) void reduce_final_k(const float2* __restrict__ partial,
                                                      float2* __restrict__ stats){
  const int w = threadIdx.x >> 6, lane = threadIdx.x & 63;
  float2 p = partial[w*64 + lane];
  float s = p.x, q = p.y;
  #pragma unroll
  for (int m = 1; m < 64; m <<= 1){ s += __shfl_xor(s, m); q += __shfl_xor(q, m); }
  if (lane == 0){
    const float inv = 1.0f/1048576.0f;
    float mean = s*inv;
    float var  = q*inv - mean*mean;
    stats[w] = make_float2(mean, rsqrtf(var + 1e-6f));
  }
}

// ---------------- weight conversion ----------------
__global__ __launch_bounds__(256) void convert_w_k(const float* __restrict__ qkv_w,
                                                   const float* __restrict__ qkv_b,
                                                   const float* __restrict__ proj_w,
                                                   unsigned short* __restrict__ Wqk,
                                                   unsigned short* __restrict__ Wv,
                                                   unsigned short* __restrict__ Wp,
                                                   float* __restrict__ bias_qk){
  int id = blockIdx.x * 256 + threadIdx.x;
  if (id < 131072){
    Wqk[id] = f2bf(qkv_w[id]);
    if (id < 512) bias_qk[id] = qkv_b[id];
  } else if (id < 196608){
    Wv[id - 131072] = f2bf(qkv_w[id]);
  } else {
    int j = id - 196608;
    Wp[j] = f2bf(proj_w[j]);
  }
}

// ---------------- GroupNorm + transpose ----------------
__global__ __launch_bounds__(256) void norm_transpose_k(const float* __restrict__ x,
                                                        const float* __restrict__ gamma,
                                                        const float* __restrict__ beta,
                                                        const float2* __restrict__ stats,
                                                        unsigned short* __restrict__ xnt){
  __shared__ float tile[64][65];
  const int b = blockIdx.z, n0 = blockIdx.x*64, c0 = blockIdx.y*64;
  const float2 st = stats[b];
  const int t = threadIdx.x;
  const int col = t & 63, rb = t >> 6;
  #pragma unroll
  for (int i = 0; i < 16; ++i){
    int rr = i*4 + rb;
    float xv = x[((size_t)b*256 + c0 + rr)*4096 + n0 + col];
    tile[rr][col] = (xv - st.x) * st.y * gamma[c0+rr] + beta[c0+rr];
  }
  __syncthreads();
  #pragma unroll
  for (int i = 0; i < 16; ++i){
    int nr = i*4 + rb;
    xnt[((size_t)b*4096 + n0 + nr)*256 + c0 + col] = f2bf(tile[col][nr]);
  }
}

// ---------------- NT GEMM ----------------
// out8 != 0 : fp8 out in A-frag tiled layout [gm/32][gn/16][gm&31][gn&15] (QK tiles)
// vtile != 0: bf16 out tiled [n/16][m/32][(n>>3)&1][m&31][n&7] (PV A-frag tiles)
__global__ __launch_bounds__(256) void gemm_nt_k(const unsigned short* __restrict__ A,
                                                 const unsigned short* __restrict__ B,
                                                 int lda, int ldb, long sA, long sB,
                                                 const float* __restrict__ bias_m,
                                                 const float* __restrict__ bias_n,
                                                 const float* __restrict__ resid, long sR,
                                                 float* __restrict__ outF,
                                                 unsigned short* __restrict__ outB,
                                                 unsigned char* __restrict__ out8,
                                                 int ldc, long sC, int vtile){
  __shared__ unsigned short As[64][40];
  __shared__ unsigned short Bs[64][40];
  const int b  = blockIdx.z;
  const int m0 = blockIdx.x * 64, n0 = blockIdx.y * 64;
  const unsigned short* Ab = A + (size_t)b * sA;
  const unsigned short* Bb = B + (size_t)b * sB;
  const int t = threadIdx.x;
  const int lane = t & 63, w = t >> 6;
  const int g = lane >> 4, r = lane & 15;
  const int wm = (w >> 1) * 32, wn = (w & 1) * 32;
  const int lrow = t >> 2, lcol = (t & 3) * 8;
  f32x4 acc00 = {0,0,0,0}, acc01 = {0,0,0,0}, acc10 = {0,0,0,0}, acc11 = {0,0,0,0};
  for (int ks = 0; ks < 8; ++ks){
    short8 av = *(const short8*)(Ab + (size_t)(m0 + lrow) * lda + ks*32 + lcol);
    short8 bv = *(const short8*)(Bb + (size_t)(n0 + lrow) * ldb + ks*32 + lcol);
    __syncthreads();
    *(short8*)&As[lrow][lcol] = av;
    *(short8*)&Bs[lrow][lcol] = bv;
    __syncthreads();
    short8 af0 = *(const short8*)&As[wm + r][g*8];
    short8 af1 = *(const short8*)&As[wm + 16 + r][g*8];
    short8 bf0 = *(const short8*)&Bs[wn + r][g*8];
    short8 bf1 = *(const short8*)&Bs[wn + 16 + r][g*8];
    acc00 = __builtin_amdgcn_mfma_f32_16x16x32_bf16(af0, bf0, acc00, 0, 0, 0);
    acc01 = __builtin_amdgcn_mfma_f32_16x16x32_bf16(af0, bf1, acc01, 0, 0, 0);
    acc10 = __builtin_amdgcn_mfma_f32_16x16x32_bf16(af1, bf0, acc10, 0, 0, 0);
    acc11 = __builtin_amdgcn_mfma_f32_16x16x32_bf16(af1, bf1, acc11, 0, 0, 0);
  }
  f32x4 accs[2][2] = {{acc00, acc01},{acc10, acc11}};
  #pragma unroll
  for (int mi = 0; mi < 2; ++mi)
    #pragma unroll
    for (int ni = 0; ni < 2; ++ni)
      #pragma unroll
      for (int j = 0; j < 4; ++j){
        int gm = m0 + wm + mi*16 + g*4 + j;
        int gn = n0 + wn + ni*16 + r;
        float vv = accs[mi][ni][j];
        if (bias_m) vv += bias_m[gm];
        if (bias_n) vv += bias_n[gn];
        if (resid)  vv += resid[(size_t)b*sR + (size_t)gm*ldc + gn];
        if (out8){
          size_t off = (size_t)b*sC + (size_t)((gm >> 5)*32 + (gn >> 4))*512
                     + (gm & 31)*16 + (gn & 15);
          out8[off] = (unsigned char)(cvt2_fp8(vv, vv) & 0xff);
        } else if (outB){
          size_t off;
          if (vtile)
            off = (size_t)b*sC + (size_t)(gn >> 4)*4096 + (size_t)(gm >> 5)*512
                + ((gn >> 3) & 1)*256 + (gm & 31)*8 + (gn & 7);
          else
            off = (size_t)b*sC + (size_t)gm*ldc + gn;
          outB[off] = f2bf(vv);
        } else {
          outF[(size_t)b*sC + (size_t)gm*ldc + gn] = vv;
        }
      }
}

// ---------------- flash attention: 8 waves = 4qw x 2cg; K in registers (tiled global) ----------------
// qk8t[b][n/32][o/16][n&31][o&15] fp8 tiles (o<256 = Q, o>=256 = K); vt bf16 PV A-frag tiles.
// K fragments loaded coalesced global->reg each iter (L2-resident); LDS holds only V dbuf + P.
// Fixed-M softmax p = exp2(S*scale - 24). ksplit=2, KVBLK=64, 32 iters, 2 barriers/iter.
__global__ __launch_bounds__(512, 1) void attn_k(const unsigned char* __restrict__ qk8,
                                                 const unsigned short* __restrict__ vt,
                                                 unsigned short* __restrict__ po,
                                                 float* __restrict__ ml){
  __shared__ __align__(16) char smem[81920];   // V dbuf 2x32KB | P 16KB
  const int id = blockIdx.x;
  const int combo = id & 7, qb = id >> 3;      // combo -> XCD (K/V L2-resident per combo)
  const int b = combo >> 1, ks = combo & 1;
  const int q0 = qb * 128;
  const int t = threadIdx.x, lane = t & 63, w = t >> 6;
  const int qw = w >> 1, cg = w & 1;
  const int hi = lane >> 5, l31 = lane & 31;
  const unsigned char* qkb = qk8 + (size_t)b * 2097152;
  const unsigned short* vtb = vt + (size_t)b * 1048576;
  char* Pb = smem + 65536;
  const float SQL2 = 0.0625f * 1.44269504088896340736f;

  // ---- Q fp8 fragments from tiled layout (coalesced 512B per slice) ----
  unsigned long long qf[16];
  {
    const unsigned char* qbase = qkb + (size_t)((q0 >> 5) + qw) * 16384 + l31*16 + hi*8;
    #pragma unroll
    for (int s = 0; s < 16; ++s)
      qf[s] = *(const unsigned long long*)(qbase + s*512);
  }

  // ---- K fragment registers (single set, reloaded after each QK consumes them) ----
  unsigned long long kr[16];
  auto loadK = [&](int kt){
    const unsigned char* kbase = qkb + (size_t)(ks*64 + kt*2 + cg) * 16384 + 8192
                               + l31*16 + hi*8;
    #pragma unroll
    for (int sl = 0; sl < 16; ++sl)
      kr[sl] = *(const unsigned long long*)(kbase + sl*512);
  };
  // stage V (32 tiles of 1KB, identity layout from pre-tiled global): 4 loads/thread
  auto stageV = [&](int kt, char* buf){
    const int kbase = ks*2048 + kt*64;
    #pragma unroll
    for (int i = 0; i < 4; ++i){
      int tix = w*4 + i;
      const unsigned short* src = vtb + (size_t)((kbase >> 4) + (tix >> 3))*4096
                                + (tix & 7)*512 + lane*8;
      gload16(src, buf + tix*1024);
    }
  };
  stageV(0, smem);
  loadK(0);

  f32x16 O[4];
  #pragma unroll
  for (int cb = 0; cb < 4; ++cb)
    #pragma unroll
    for (int jj = 0; jj < 16; ++jj) O[cb][jj] = 0.f;
  float lrun = 0.f;

  for (int kt = 0; kt < 32; ++kt){
    char* Vt = smem + (kt & 1)*32768;
    char* Vn = smem + ((kt + 1) & 1)*32768;
    const int ktn = (kt < 31) ? kt + 1 : 31;

    WAITV(0);     // V(t) staged + K(t) regs landed (all issued >= half an iter ago)
    BARRIER();    // all waves' V(t) visible; Vn buffer free

    stageV(ktn, Vn);   // issue next V early: covered by QK+SM+PV

    // ---- S^T = K . Q : 16 fp8 MFMA from registers, 2 chains ----
    f32x16 Sa, Sb;
    #pragma unroll
    for (int jj = 0; jj < 16; ++jj){ Sa[jj] = 0.f; Sb[jj] = 0.f; }
    __builtin_amdgcn_s_setprio(1);
    #pragma unroll
    for (int s = 0; s < 8; ++s){
      Sa = __builtin_amdgcn_mfma_f32_32x32x16_fp8_fp8((long long)kr[2*s  ], (long long)qf[2*s  ], Sa, 0, 0, 0);
      Sb = __builtin_amdgcn_mfma_f32_32x32x16_fp8_fp8((long long)kr[2*s+1], (long long)qf[2*s+1], Sb, 0, 0, 0);
    }
    __builtin_amdgcn_s_setprio(0);

    loadK(ktn);   // reuse kr (WAR after QK reads); covered by SM+PV+barrier

    // ---- fixed-M softmax + pack ----
    float p[16];
    #pragma unroll
    for (int jj = 0; jj < 16; ++jj) p[jj] = exp2f(fmaf(Sa[jj] + Sb[jj], SQL2, -24.0f));
    lrun += ((p[0]+p[1]) + (p[2]+p[3])) + ((p[4]+p[5]) + (p[6]+p[7]))
          + ((p[8]+p[9]) + (p[10]+p[11])) + ((p[12]+p[13]) + (p[14]+p[15]));
    unsigned int a0 = cvtpk_bf16(p[0],p[1]),   a1 = cvtpk_bf16(p[2],p[3]);
    unsigned int a2 = cvtpk_bf16(p[4],p[5]),   a3 = cvtpk_bf16(p[6],p[7]);
    unsigned int a4 = cvtpk_bf16(p[8],p[9]),   a5 = cvtpk_bf16(p[10],p[11]);
    unsigned int a6 = cvtpk_bf16(p[12],p[13]), a7 = cvtpk_bf16(p[14],p[15]);
    asm("v_permlane32_swap_b32 %0, %1" : "+v"(a0), "+v"(a2));
    asm("v_permlane32_swap_b32 %0, %1" : "+v"(a1), "+v"(a3));
    asm("v_permlane32_swap_b32 %0, %1" : "+v"(a4), "+v"(a6));
    asm("v_permlane32_swap_b32 %0, %1" : "+v"(a5), "+v"(a7));
    i32x4 u0 = {(int)a0,(int)a1,(int)a2,(int)a3};
    i32x4 u1 = {(int)a4,(int)a5,(int)a6,(int)a7};
    short8 pa0 = __builtin_bit_cast(short8, u0);   // local slice -> global k-slice 2cg
    short8 pa1 = __builtin_bit_cast(short8, u1);   // global k-slice 2cg+1
    *(short8*)(Pb + (qw*4 + cg*2    )*1024 + lane*16) = pa0;
    *(short8*)(Pb + (qw*4 + cg*2 + 1)*1024 + lane*16) = pa1;

    WAITLGKM0();    // my P writes done
    BARRIER();      // all P visible

    // ---- read partner P, order slices; O += V.P^T : 4 k-slices x 4 c-blocks ----
    short8 qb0 = *(const short8*)(Pb + (qw*4 + (1-cg)*2    )*1024 + lane*16);
    short8 qb1 = *(const short8*)(Pb + (qw*4 + (1-cg)*2 + 1)*1024 + lane*16);
    short8 pf0 = cg ? qb0 : pa0;
    short8 pf1 = cg ? qb1 : pa1;
    short8 pf2 = cg ? pa0 : qb0;
    short8 pf3 = cg ? pa1 : qb1;
    __builtin_amdgcn_s_setprio(1);
    #pragma unroll
    for (int cb = 0; cb < 4; ++cb){
      short8 v0 = *(const short8*)(Vt + (0*8 + cg*4 + cb)*1024 + lane*16);
      O[cb] = __builtin_amdgcn_mfma_f32_32x32x16_bf16(v0, pf0, O[cb], 0, 0, 0);
      short8 v1 = *(const short8*)(Vt + (1*8 + cg*4 + cb)*1024 + lane*16);
      O[cb] = __builtin_amdgcn_mfma_f32_32x32x16_bf16(v1, pf1, O[cb], 0, 0, 0);
      short8 v2 = *(const short8*)(Vt + (2*8 + cg*4 + cb)*1024 + lane*16);
      O[cb] = __builtin_amdgcn_mfma_f32_32x32x16_bf16(v2, pf2, O[cb], 0, 0, 0);
      short8 v3 = *(const short8*)(Vt + (3*8 + cg*4 + cb)*1024 + lane*16);
      O[cb] = __builtin_amdgcn_mfma_f32_32x32x16_bf16(v3, pf3, O[cb], 0, 0, 0);
    }
    __builtin_amdgcn_s_setprio(0);
  }
  WAITV(0);   // drain tail stages before epilogue

  // ---- epilogue: unnormalized partials + l partials ----
  float lf = lrun + __shfl_xor(lrun, 32);
  const int qg = q0 + qw*32 + l31;
  unsigned short* pob = po + (size_t)combo * 1048576;   // [256 c][4096 q]
  #pragma unroll
  for (int cb = 0; cb < 4; ++cb)
    #pragma unroll
    for (int jj = 0; jj < 16; ++jj){
      int c = cg*128 + cb*32 + (jj & 3) + 8*(jj >> 2) + 4*hi;
      pob[(size_t)c*4096 + qg] = f2bf(O[cb][jj]);
    }
  if (lane < 32)
    ml[(size_t)(combo*2 + cg)*4096 + qg] = lf;
}

// ---------------- merge the 2 k-chunks: out ho[b][q][c] bf16 ----------------
__global__ __launch_bounds__(256) void attn_merge_k(const unsigned short* __restrict__ po,
                                                    const float* __restrict__ ml,
                                                    unsigned short* __restrict__ ho){
  __shared__ float Of[64][261];
  const int b = blockIdx.y, q0 = blockIdx.x * 64;
  const int t = threadIdx.x, ql = t & 63, ci = t >> 6;
  const int q = q0 + ql;
  float L = ml[(size_t)((b*2+0)*2 + 0)*4096 + q] + ml[(size_t)((b*2+0)*2 + 1)*4096 + q]
          + ml[(size_t)((b*2+1)*2 + 0)*4096 + q] + ml[(size_t)((b*2+1)*2 + 1)*4096 + q];
  float inv = 1.0f / L;
  const unsigned short* p0 = po + (size_t)(b*2+0)*1048576 + q;
  const unsigned short* p1 = po + (size_t)(b*2+1)*1048576 + q;
  #pragma unroll
  for (int i = 0; i < 64; ++i){
    int c = ci + 4*i;
    float v = bf2f(p0[(size_t)c*4096]) + bf2f(p1[(size_t)c*4096]);
    Of[ql][c] = v * inv;
  }
  __syncthreads();
  const int qr = t >> 2, sub = t & 3;
  const float* rowp = Of[qr];
  unsigned short* dst = ho + ((size_t)(b*4096 + q0 + qr))*256;
  #pragma unroll
  for (int jj = 0; jj < 8; ++jj){
    int c = sub*8 + jj*32;
    float4 v0 = *(const float4*)(rowp + c);
    float4 v1 = *(const float4*)(rowp + c + 4);
    short8 o;
    o[0] = (short)f2bf(v0.x); o[1] = (short)f2bf(v0.y);
    o[2] = (short)f2bf(v0.z); o[3] = (short)f2bf(v0.w);
    o[4] = (short)f2bf(v1.x); o[5] = (short)f2bf(v1.y);
    o[6] = (short)f2bf(v1.z); o[7] = (short)f2bf(v1.w);
    *(short8*)(dst + c) = o;
  }
}

// ---------------- launch ----------------
extern "C" void kernel_launch(void* const* d_in, const int* in_sizes, int n_in,
                              void* d_out, int out_size, void* d_ws, size_t ws_size,
                              hipStream_t stream){
  const float* x      = (const float*)d_in[0];
  const float* gamma  = (const float*)d_in[1];
  const float* beta   = (const float*)d_in[2];
  const float* qkv_w  = (const float*)d_in[3];
  const float* qkv_b  = (const float*)d_in[4];
  const float* proj_w = (const float*)d_in[5];
  const float* proj_b = (const float*)d_in[6];
  float* out = (float*)d_out;
  char* ws = (char*)d_ws;

  float2* partial        = (float2*)(ws + 0);
  float2* stats          = (float2*)(ws + 2048);
  float*  bias_qk        = (float*)(ws + 4096);
  unsigned short* Wqk    = (unsigned short*)(ws + 8192);      // 512x256 bf16
  unsigned short* Wv     = (unsigned short*)(ws + 270336);    // 256x256
  unsigned short* Wp     = (unsigned short*)(ws + 401408);    // 256x256
  unsigned short* xnt    = (unsigned short*)(ws + 532480);    // 4x4096x256 bf16 (8.4 MB)
  unsigned char*  qk8    = (unsigned char*)(ws + 8921088);    // 4x2MB fp8 tiled (8.4 MB)
  unsigned short* vt     = (unsigned short*)(ws + 17309696);  // 4x1M bf16 tiled (8.4 MB)
  unsigned short* po     = (unsigned short*)(ws + 25698304);  // 8x256x4096 bf16 (16.8 MB)
  float*          ml     = (float*)(ws + 42475520);           // 8x2x4096 f32 (256 KB)
  unsigned short* ho     = xnt;  // xnt dead after QKV gemms -> reuse

  reduce_partial_k<<<dim3(64,4), 256, 0, stream>>>(x, partial);
  reduce_final_k<<<1, 256, 0, stream>>>(partial, stats);
  convert_w_k<<<1024, 256, 0, stream>>>(qkv_w, qkv_b, proj_w, Wqk, Wv, Wp, bias_qk);
  norm_transpose_k<<<dim3(64,4,4), 256, 0, stream>>>(x, gamma, beta, stats, xnt);
  // q,k fp8 tiled: qk8t[b]
  gemm_nt_k<<<dim3(64,8,4), 256, 0, stream>>>(xnt, Wqk, 256, 256, 4096L*256, 0,
      nullptr, bias_qk, nullptr, 0, nullptr, nullptr, qk8, 512, 4096L*512, 0);
  // v bf16 tiled
  gemm_nt_k<<<dim3(4,64,4), 256, 0, stream>>>(Wv, xnt, 256, 256, 0, 4096L*256,
      qkv_b + 512, nullptr, nullptr, 0, nullptr, vt, nullptr, 4096, 256L*4096, 1);
  attn_k<<<dim3(256), 512, 0, stream>>>(qk8, vt, po, ml);
  attn_merge_k<<<dim3(64,4), 256, 0, stream>>>(po, ml, ho);
  // out = proj(ho) + x
  gemm_nt_k<<<dim3(4,64,4), 256, 0, stream>>>(Wp, ho, 256, 256, 0, 4096L*256,
      proj_b, nullptr, x, 1048576L, out, nullptr, nullptr, 4096, 1048576L, 0);
}

// Round 13
// 135.283 us; speedup vs baseline: 1.2600x; 1.2600x over previous
//
#include <hip/hip_runtime.h>

typedef __attribute__((ext_vector_type(8))) short short8;
typedef __attribute__((ext_vector_type(4))) float f32x4;
typedef __attribute__((ext_vector_type(16))) float f32x16;
typedef __attribute__((ext_vector_type(4))) int i32x4;

__device__ __forceinline__ unsigned short f2bf(float f){
  union { float f; unsigned int u; } cv; cv.f = f;
  unsigned int u = cv.u;
  u = (u + 0x7fffu + ((u >> 16) & 1u)) >> 16;
  return (unsigned short)u;
}
__device__ __forceinline__ float bf2f(unsigned short h){
  union { unsigned int u; float f; } cv; cv.u = ((unsigned int)h) << 16;
  return cv.f;
}

typedef unsigned int u32g __attribute__((address_space(1)));
typedef unsigned int u32l __attribute__((address_space(3)));
__device__ __forceinline__ void gload16(const void* g, void* l){
  __builtin_amdgcn_global_load_lds((const u32g*)g, (u32l*)l, 16, 0, 0);
}

__device__ __forceinline__ unsigned int cvtpk_bf16(float lo, float hi){
  unsigned int r;
  asm("v_cvt_pk_bf16_f32 %0, %1, %2" : "=v"(r) : "v"(lo), "v"(hi));
  return r;
}
__device__ __forceinline__ unsigned int cvt2_fp8(float a, float b){
  unsigned int r;
  asm("v_cvt_pk_fp8_f32 %0, %1, %2" : "=v"(r) : "v"(a), "v"(b));
  return r;
}

#define BARRIER() asm volatile("s_barrier" ::: "memory")
#define WAITV(N)  asm volatile("s_waitcnt vmcnt(" #N ")" ::: "memory")
#define WAITLGKM0() asm volatile("s_waitcnt lgkmcnt(0)" ::: "memory")

// ---------------- fused: per-batch partial reduction (blocks 0..255) + weight convert (256..1279) ----
__global__ __launch_bounds__(256) void fused_pre_k(const float* __restrict__ x,
                                                   float2* __restrict__ partial,
                                                   const float* __restrict__ qkv_w,
                                                   const float* __restrict__ qkv_b,
                                                   const float* __restrict__ proj_w,
                                                   unsigned short* __restrict__ Wqk,
                                                   unsigned short* __restrict__ Wv,
                                                   unsigned short* __restrict__ Wp,
                                                   float* __restrict__ bias_qk){
  const int blk = blockIdx.x;
  if (blk < 256){
    const int b = blk >> 6, xb = blk & 63;
    const float4* xp = (const float4*)(x + (size_t)b*1048576 + (size_t)xb*16384);
    float s = 0.f, sq = 0.f;
    #pragma unroll
    for (int i = 0; i < 16; ++i){
      float4 v = xp[threadIdx.x + i*256];
      s  += v.x + v.y + v.z + v.w;
      sq += v.x*v.x + v.y*v.y + v.z*v.z + v.w*v.w;
    }
    #pragma unroll
    for (int m = 1; m < 64; m <<= 1){ s += __shfl_xor(s, m); sq += __shfl_xor(sq, m); }
    __shared__ float2 acc[4];
    if ((threadIdx.x & 63) == 0) acc[threadIdx.x >> 6] = make_float2(s, sq);
    __syncthreads();
    if (threadIdx.x == 0){
      float S = 0.f, Q = 0.f;
      for (int i = 0; i < 4; ++i){ S += acc[i].x; Q += acc[i].y; }
      partial[b*64 + xb] = make_float2(S, Q);
    }
  } else {
    int id = (blk - 256) * 256 + threadIdx.x;
    if (id < 131072){
      Wqk[id] = f2bf(qkv_w[id]);
      if (id < 512) bias_qk[id] = qkv_b[id];
    } else if (id < 196608){
      Wv[id - 131072] = f2bf(qkv_w[id]);
    } else {
      int j = id - 196608;
      Wp[j] = f2bf(proj_w[j]);
    }
  }
}

// ---------------- GroupNorm + transpose (final stat reduce done per-block, redundantly) ----------
__global__ __launch_bounds__(256) void norm_transpose_k(const float* __restrict__ x,
                                                        const float* __restrict__ gamma,
                                                        const float* __restrict__ beta,
                                                        const float2* __restrict__ partial,
                                                        unsigned short* __restrict__ xnt){
  __shared__ float tile[64][65];
  __shared__ float2 stt;
  const int b = blockIdx.z, n0 = blockIdx.x*64, c0 = blockIdx.y*64;
  const int t = threadIdx.x;
  if (t < 64){
    float2 p = partial[b*64 + t];
    float s = p.x, q = p.y;
    #pragma unroll
    for (int m = 1; m < 64; m <<= 1){ s += __shfl_xor(s, m); q += __shfl_xor(q, m); }
    if (t == 0){
      const float inv = 1.0f/1048576.0f;
      float mean = s*inv;
      float var  = q*inv - mean*mean;
      stt = make_float2(mean, rsqrtf(var + 1e-6f));
    }
  }
  __syncthreads();
  const float2 st = stt;
  const int col = t & 63, rb = t >> 6;
  #pragma unroll
  for (int i = 0; i < 16; ++i){
    int rr = i*4 + rb;
    float xv = x[((size_t)b*256 + c0 + rr)*4096 + n0 + col];
    tile[rr][col] = (xv - st.x) * st.y * gamma[c0+rr] + beta[c0+rr];
  }
  __syncthreads();
  #pragma unroll
  for (int i = 0; i < 16; ++i){
    int nr = i*4 + rb;
    xnt[((size_t)b*4096 + n0 + nr)*256 + c0 + col] = f2bf(tile[col][nr]);
  }
}

// ---------------- NT GEMM ----------------
// out8 != 0 : fp8 e4m3 bytes at [gm][gn] (ldc stride)
// vtile != 0: bf16 out tiled [n/16][m/32][(n>>3)&1][m&31][n&7] (PV A-frag tiles)
__global__ __launch_bounds__(256) void gemm_nt_k(const unsigned short* __restrict__ A,
                                                 const unsigned short* __restrict__ B,
                                                 int lda, int ldb, long sA, long sB,
                                                 const float* __restrict__ bias_m,
                                                 const float* __restrict__ bias_n,
                                                 const float* __restrict__ resid, long sR,
                                                 float* __restrict__ outF,
                                                 unsigned short* __restrict__ outB,
                                                 unsigned char* __restrict__ out8,
                                                 int ldc, long sC, int vtile){
  __shared__ unsigned short As[64][40];
  __shared__ unsigned short Bs[64][40];
  const int b  = blockIdx.z;
  const int m0 = blockIdx.x * 64, n0 = blockIdx.y * 64;
  const unsigned short* Ab = A + (size_t)b * sA;
  const unsigned short* Bb = B + (size_t)b * sB;
  const int t = threadIdx.x;
  const int lane = t & 63, w = t >> 6;
  const int g = lane >> 4, r = lane & 15;
  const int wm = (w >> 1) * 32, wn = (w & 1) * 32;
  const int lrow = t >> 2, lcol = (t & 3) * 8;
  f32x4 acc00 = {0,0,0,0}, acc01 = {0,0,0,0}, acc10 = {0,0,0,0}, acc11 = {0,0,0,0};
  for (int ks = 0; ks < 8; ++ks){
    short8 av = *(const short8*)(Ab + (size_t)(m0 + lrow) * lda + ks*32 + lcol);
    short8 bv = *(const short8*)(Bb + (size_t)(n0 + lrow) * ldb + ks*32 + lcol);
    __syncthreads();
    *(short8*)&As[lrow][lcol] = av;
    *(short8*)&Bs[lrow][lcol] = bv;
    __syncthreads();
    short8 af0 = *(const short8*)&As[wm + r][g*8];
    short8 af1 = *(const short8*)&As[wm + 16 + r][g*8];
    short8 bf0 = *(const short8*)&Bs[wn + r][g*8];
    short8 bf1 = *(const short8*)&Bs[wn + 16 + r][g*8];
    acc00 = __builtin_amdgcn_mfma_f32_16x16x32_bf16(af0, bf0, acc00, 0, 0, 0);
    acc01 = __builtin_amdgcn_mfma_f32_16x16x32_bf16(af0, bf1, acc01, 0, 0, 0);
    acc10 = __builtin_amdgcn_mfma_f32_16x16x32_bf16(af1, bf0, acc10, 0, 0, 0);
    acc11 = __builtin_amdgcn_mfma_f32_16x16x32_bf16(af1, bf1, acc11, 0, 0, 0);
  }
  f32x4 accs[2][2] = {{acc00, acc01},{acc10, acc11}};
  #pragma unroll
  for (int mi = 0; mi < 2; ++mi)
    #pragma unroll
    for (int ni = 0; ni < 2; ++ni)
      #pragma unroll
      for (int j = 0; j < 4; ++j){
        int gm = m0 + wm + mi*16 + g*4 + j;
        int gn = n0 + wn + ni*16 + r;
        float vv = accs[mi][ni][j];
        if (bias_m) vv += bias_m[gm];
        if (bias_n) vv += bias_n[gn];
        if (resid)  vv += resid[(size_t)b*sR + (size_t)gm*ldc + gn];
        if (out8){
          out8[(size_t)b*sC + (size_t)gm*ldc + gn] = (unsigned char)(cvt2_fp8(vv, vv) & 0xff);
        } else if (outB){
          size_t off;
          if (vtile)
            off = (size_t)b*sC + (size_t)(gn >> 4)*4096 + (size_t)(gm >> 5)*512
                + ((gn >> 3) & 1)*256 + (gm & 31)*8 + (gn & 7);
          else
            off = (size_t)b*sC + (size_t)gm*ldc + gn;
          outB[off] = f2bf(vv);
        } else {
          outF[(size_t)b*sC + (size_t)gm*ldc + gn] = vv;
        }
      }
}

// ---------------- flash attention: 8 waves = 4qw x 2cg, fp8 QK, counted-vmcnt dbuf (R9) ----------------
// qk8[b][n][512B] fp8 (Q 0..255, K 256..511); vt bf16 PV A-frag tiles.
// Fixed-M softmax p = exp2(S*scale - 24). ksplit=2. Per iter: vmcnt(4) / vmcnt(2), 2 barriers.
__global__ __launch_bounds__(512, 1) void attn_k(const unsigned char* __restrict__ qk8,
                                                 const unsigned short* __restrict__ vt,
                                                 unsigned short* __restrict__ po,
                                                 float* __restrict__ ml){
  __shared__ __align__(16) char smem[114688];  // 2 x (K 16KB | V 32KB) dbuf + P 16KB
  const int id = blockIdx.x;
  const int combo = id & 7, qb = id >> 3;      // combo -> XCD (K/V L2-resident per combo)
  const int b = combo >> 1, ks = combo & 1;
  const int q0 = qb * 128;
  const int t = threadIdx.x, lane = t & 63, w = t >> 6;
  const int qw = w >> 1, cg = w & 1;
  const int hi = lane >> 5, l31 = lane & 31;
  const unsigned char* qkb = qk8 + (size_t)b * 4096 * 512;
  const unsigned short* vtb = vt + (size_t)b * 1048576;
  char* Pb = smem + 98304;
  const float SQL2 = 0.0625f * 1.44269504088896340736f;

  // ---- Q fp8 fragments: wave owns q-rows q0 + qw*32 + l31 (B-operand) ----
  unsigned long long qf[16];
  {
    const unsigned char* qrow = qkb + (size_t)(q0 + qw*32 + l31) * 512;
    #pragma unroll
    for (int s = 0; s < 16; ++s) qf[s] = *(const unsigned long long*)(qrow + s*16 + hi*8);
  }

  // stage K tile (64 rows x 256B fp8): 2 loads/thread. XOR-swizzled source, linear dest.
  auto stageK = [&](int kt, char* buf){
    const int kbase = ks*2048 + kt*64;
    #pragma unroll
    for (int i2 = 0; i2 < 2; ++i2){
      int ci = w*128 + i2*64 + lane;
      int r = ci >> 4;
      const unsigned char* src = qkb + (size_t)(kbase + r)*512 + 256
                               + (((ci & 15) ^ (r & 15)) * 16);
      gload16(src, buf + w*2048 + i2*1024);
    }
  };
  // stage V (32 tiles of 1KB, identity layout from pre-tiled global): 4 loads/thread
  auto stageV = [&](int kt, char* buf){
    const int kbase = ks*2048 + kt*64;
    #pragma unroll
    for (int i = 0; i < 4; ++i){
      int tix = w*4 + i;
      const unsigned short* src = vtb + (size_t)((kbase >> 4) + (tix >> 3))*4096
                                + (tix & 7)*512 + lane*8;
      gload16(src, buf + 16384 + tix*1024);
    }
  };
  stageK(0, smem);   // 2 loads in flight
  stageV(0, smem);   // +4 = 6

  f32x16 O[4];
  #pragma unroll
  for (int cb = 0; cb < 4; ++cb)
    #pragma unroll
    for (int jj = 0; jj < 16; ++jj) O[cb][jj] = 0.f;
  float lrun = 0.f;
  const int ksw = (l31 & 15) << 4;

  for (int kt = 0; kt < 32; ++kt){
    char* cur = smem + (kt & 1)*49152;
    char* nxt = smem + ((kt + 1) & 1)*49152;

    WAITV(4);     // my K(t) landed; V(t)'s 4 stay counted
    BARRIER();    // all waves' K(t) visible; prev buffer fully consumed

    // ---- S^T = K[cg 32k] . Q : 16 fp8 MFMA, 2 chains ----
    f32x16 Sa, Sb;
    #pragma unroll
    for (int jj = 0; jj < 16; ++jj){ Sa[jj] = 0.f; Sb[jj] = 0.f; }
    const char* kp = cur + (cg*32 + l31)*256;
    __builtin_amdgcn_s_setprio(1);
    #pragma unroll
    for (int s = 0; s < 8; ++s){
      unsigned long long k0 = *(const unsigned long long*)(kp + (((2*s  )*16 + hi*8) ^ ksw));
      unsigned long long k1 = *(const unsigned long long*)(kp + (((2*s+1)*16 + hi*8) ^ ksw));
      Sa = __builtin_amdgcn_mfma_f32_32x32x16_fp8_fp8((long long)k0, (long long)qf[2*s  ], Sa, 0, 0, 0);
      Sb = __builtin_amdgcn_mfma_f32_32x32x16_fp8_fp8((long long)k1, (long long)qf[2*s+1], Sb, 0, 0, 0);
    }
    __builtin_amdgcn_s_setprio(0);

    int ktn = (kt < 31) ? kt + 1 : 31;
    stageK(ktn, nxt);   // K region of nxt free since top barrier; covered by SM+PV

    // ---- fixed-M softmax + pack (raw v_exp_f32) ----
    float p[16];
    #pragma unroll
    for (int jj = 0; jj < 16; ++jj)
      p[jj] = __builtin_amdgcn_exp2f(fmaf(Sa[jj] + Sb[jj], SQL2, -24.0f));
    lrun += ((p[0]+p[1]) + (p[2]+p[3])) + ((p[4]+p[5]) + (p[6]+p[7]))
          + ((p[8]+p[9]) + (p[10]+p[11])) + ((p[12]+p[13]) + (p[14]+p[15]));
    unsigned int a0 = cvtpk_bf16(p[0],p[1]),   a1 = cvtpk_bf16(p[2],p[3]);
    unsigned int a2 = cvtpk_bf16(p[4],p[5]),   a3 = cvtpk_bf16(p[6],p[7]);
    unsigned int a4 = cvtpk_bf16(p[8],p[9]),   a5 = cvtpk_bf16(p[10],p[11]);
    unsigned int a6 = cvtpk_bf16(p[12],p[13]), a7 = cvtpk_bf16(p[14],p[15]);
    asm("v_permlane32_swap_b32 %0, %1" : "+v"(a0), "+v"(a2));
    asm("v_permlane32_swap_b32 %0, %1" : "+v"(a1), "+v"(a3));
    asm("v_permlane32_swap_b32 %0, %1" : "+v"(a4), "+v"(a6));
    asm("v_permlane32_swap_b32 %0, %1" : "+v"(a5), "+v"(a7));
    i32x4 u0 = {(int)a0,(int)a1,(int)a2,(int)a3};
    i32x4 u1 = {(int)a4,(int)a5,(int)a6,(int)a7};
    short8 pa0 = __builtin_bit_cast(short8, u0);   // k-slice cg*2
    short8 pa1 = __builtin_bit_cast(short8, u1);   // k-slice cg*2+1
    *(short8*)(Pb + (qw*4 + cg*2    )*1024 + lane*16) = pa0;
    *(short8*)(Pb + (qw*4 + cg*2 + 1)*1024 + lane*16) = pa1;

    WAITV(2);       // my V(t) landed (K(t+1)'s 2 stay in flight)
    WAITLGKM0();    // my P writes done
    BARRIER();      // all P + all V(t) visible

    stageV(ktn, nxt);  // V region of nxt free; covered by PV + next QK

    // ---- read partner P, O += V . P^T : 4 k-slices x 4 c-blocks ----
    short8 qb0 = *(const short8*)(Pb + (qw*4 + (1-cg)*2    )*1024 + lane*16);
    short8 qb1 = *(const short8*)(Pb + (qw*4 + (1-cg)*2 + 1)*1024 + lane*16);
    short8 pf0 = cg ? qb0 : pa0;
    short8 pf1 = cg ? qb1 : pa1;
    short8 pf2 = cg ? pa0 : qb0;
    short8 pf3 = cg ? pa1 : qb1;
    const char* Vt = cur + 16384;
    __builtin_amdgcn_s_setprio(1);
    #pragma unroll
    for (int cb = 0; cb < 4; ++cb){
      short8 v0 = *(const short8*)(Vt + (0*8 + cg*4 + cb)*1024 + lane*16);
      O[cb] = __builtin_amdgcn_mfma_f32_32x32x16_bf16(v0, pf0, O[cb], 0, 0, 0);
      short8 v1 = *(const short8*)(Vt + (1*8 + cg*4 + cb)*1024 + lane*16);
      O[cb] = __builtin_amdgcn_mfma_f32_32x32x16_bf16(v1, pf1, O[cb], 0, 0, 0);
      short8 v2 = *(const short8*)(Vt + (2*8 + cg*4 + cb)*1024 + lane*16);
      O[cb] = __builtin_amdgcn_mfma_f32_32x32x16_bf16(v2, pf2, O[cb], 0, 0, 0);
      short8 v3 = *(const short8*)(Vt + (3*8 + cg*4 + cb)*1024 + lane*16);
      O[cb] = __builtin_amdgcn_mfma_f32_32x32x16_bf16(v3, pf3, O[cb], 0, 0, 0);
    }
    __builtin_amdgcn_s_setprio(0);
  }
  WAITV(0);   // drain tail stages before endpgm

  // ---- epilogue: unnormalized partials + l partials ----
  float lf = lrun + __shfl_xor(lrun, 32);
  const int qg = q0 + qw*32 + l31;
  unsigned short* pob = po + (size_t)combo * 1048576;   // [256 c][4096 q]
  #pragma unroll
  for (int cb = 0; cb < 4; ++cb)
    #pragma unroll
    for (int jj = 0; jj < 16; ++jj){
      int c = cg*128 + cb*32 + (jj & 3) + 8*(jj >> 2) + 4*hi;
      pob[(size_t)c*4096 + qg] = f2bf(O[cb][jj]);
    }
  if (lane < 32)
    ml[(size_t)(combo*2 + cg)*4096 + qg] = lf;
}

// ---------------- merge the 2 k-chunks: out ho[b][q][c] bf16 ----------------
__global__ __launch_bounds__(256) void attn_merge_k(const unsigned short* __restrict__ po,
                                                    const float* __restrict__ ml,
                                                    unsigned short* __restrict__ ho){
  __shared__ float Of[64][261];
  const int b = blockIdx.y, q0 = blockIdx.x * 64;
  const int t = threadIdx.x, ql = t & 63, ci = t >> 6;
  const int q = q0 + ql;
  float L = ml[(size_t)((b*2+0)*2 + 0)*4096 + q] + ml[(size_t)((b*2+0)*2 + 1)*4096 + q]
          + ml[(size_t)((b*2+1)*2 + 0)*4096 + q] + ml[(size_t)((b*2+1)*2 + 1)*4096 + q];
  float inv = 1.0f / L;
  const unsigned short* p0 = po + (size_t)(b*2+0)*1048576 + q;
  const unsigned short* p1 = po + (size_t)(b*2+1)*1048576 + q;
  #pragma unroll
  for (int i = 0; i < 64; ++i){
    int c = ci + 4*i;
    float v = bf2f(p0[(size_t)c*4096]) + bf2f(p1[(size_t)c*4096]);
    Of[ql][c] = v * inv;
  }
  __syncthreads();
  const int qr = t >> 2, sub = t & 3;
  const float* rowp = Of[qr];
  unsigned short* dst = ho + ((size_t)(b*4096 + q0 + qr))*256;
  #pragma unroll
  for (int jj = 0; jj < 8; ++jj){
    int c = sub*8 + jj*32;
    float4 v0 = *(const float4*)(rowp + c);
    float4 v1 = *(const float4*)(rowp + c + 4);
    short8 o;
    o[0] = (short)f2bf(v0.x); o[1] = (short)f2bf(v0.y);
    o[2] = (short)f2bf(v0.z); o[3] = (short)f2bf(v0.w);
    o[4] = (short)f2bf(v1.x); o[5] = (short)f2bf(v1.y);
    o[6] = (short)f2bf(v1.z); o[7] = (short)f2bf(v1.w);
    *(short8*)(dst + c) = o;
  }
}

// ---------------- launch ----------------
extern "C" void kernel_launch(void* const* d_in, const int* in_sizes, int n_in,
                              void* d_out, int out_size, void* d_ws, size_t ws_size,
                              hipStream_t stream){
  const float* x      = (const float*)d_in[0];
  const float* gamma  = (const float*)d_in[1];
  const float* beta   = (const float*)d_in[2];
  const float* qkv_w  = (const float*)d_in[3];
  const float* qkv_b  = (const float*)d_in[4];
  const float* proj_w = (const float*)d_in[5];
  const float* proj_b = (const float*)d_in[6];
  float* out = (float*)d_out;
  char* ws = (char*)d_ws;

  float2* partial        = (float2*)(ws + 0);
  float*  bias_qk        = (float*)(ws + 4096);
  unsigned short* Wqk    = (unsigned short*)(ws + 8192);      // 512x256 bf16
  unsigned short* Wv     = (unsigned short*)(ws + 270336);    // 256x256
  unsigned short* Wp     = (unsigned short*)(ws + 401408);    // 256x256
  unsigned short* xnt    = (unsigned short*)(ws + 532480);    // 4x4096x256 bf16 (8.4 MB)
  unsigned char*  qk8    = (unsigned char*)(ws + 8921088);    // 4x4096x512 fp8 (8.4 MB)
  unsigned short* vt     = (unsigned short*)(ws + 17309696);  // 4x1M bf16 tiled (8.4 MB)
  unsigned short* po     = (unsigned short*)(ws + 25698304);  // 8x256x4096 bf16 (16.8 MB)
  float*          ml     = (float*)(ws + 42475520);           // 8x2x4096 f32 (256 KB)
  unsigned short* ho     = xnt;  // xnt dead after QKV gemms -> reuse

  fused_pre_k<<<1280, 256, 0, stream>>>(x, partial, qkv_w, qkv_b, proj_w,
                                        Wqk, Wv, Wp, bias_qk);
  norm_transpose_k<<<dim3(64,4,4), 256, 0, stream>>>(x, gamma, beta, partial, xnt);
  // q,k fp8: qk8[b][n][o]
  gemm_nt_k<<<dim3(64,8,4), 256, 0, stream>>>(xnt, Wqk, 256, 256, 4096L*256, 0,
      nullptr, bias_qk, nullptr, 0, nullptr, nullptr, qk8, 512, 4096L*512, 0);
  // v bf16 tiled
  gemm_nt_k<<<dim3(4,64,4), 256, 0, stream>>>(Wv, xnt, 256, 256, 0, 4096L*256,
      qkv_b + 512, nullptr, nullptr, 0, nullptr, vt, nullptr, 4096, 256L*4096, 1);
  attn_k<<<dim3(256), 512, 0, stream>>>(qk8, vt, po, ml);
  attn_merge_k<<<dim3(64,4), 256, 0, stream>>>(po, ml, ho);
  // out = proj(ho) + x
  gemm_nt_k<<<dim3(4,64,4), 256, 0, stream>>>(Wp, ho, 256, 256, 0, 4096L*256,
      proj_b, nullptr, x, 1048576L, out, nullptr, nullptr, 4096, 1048576L, 0);
}